// Round 4
// baseline (582.530 us; speedup 1.0000x reference)
//
#include <hip/hip_runtime.h>
#include <stdint.h>

#define THREADS 256
#define SPB 8                  // samples per block -> 32 A-rows
#define CHUNK_WORDS 4096       // one K=16 W chunk: hi plane 2048 + lo plane 2048 words
#define NCHUNK_TOT 64          // 4 layers x 16 chunks, linearized

typedef _Float16 f16x8 __attribute__((ext_vector_type(8)));
typedef float f32x16 __attribute__((ext_vector_type(16)));

union FragH { uint32_t u[4]; f16x8 v; };

__device__ __forceinline__ uint32_t f2h(float f) {     // RNE f32->f16 bits
    _Float16 h = (_Float16)f;                          // v_cvt_f16_f32 (RNE)
    return (uint32_t)__builtin_bit_cast(uint16_t, h);
}
__device__ __forceinline__ float h2f(uint32_t b) {
    return (float)__builtin_bit_cast(_Float16, (uint16_t)(b & 0xffffu));
}
__device__ __forceinline__ uint32_t packh(float a, float b) {  // f16(a)|f16(b)<<16
    return f2h(a) | (f2h(b) << 16);
}
__device__ __forceinline__ float wsum(float v) {
    #pragma unroll
    for (int off = 32; off > 0; off >>= 1) v += __shfl_xor(v, off, 64);
    return v;
}
__device__ __forceinline__ float wmax(float v) {
    #pragma unroll
    for (int off = 32; off > 0; off >>= 1) v = fmaxf(v, __shfl_xor(v, off, 64));
    return v;
}

// ---- pre-kernel: pack W into planar hi/lo f16 k-pair chunk images ----
// word idx = l*65536 + kt*4096 + plane*2048 + s8*1024 + n*4 + w
// PAIR PERMUTATION: pair index kp = kt*8 + s8*4 + w holds logical k's
//   klo(kp) = 2*(kp & ~31) + (kp & 31)   and   khi = klo + 32
// so a lane's two output columns (n, n+32) form one f16 k-pair IN-LANE.
// plane0 = f16 RNE of w; plane1 = f16 of residual (B gets ~22 effective bits).
__global__ __launch_bounds__(256) void pack_w(const float* __restrict__ w_hid,
                                              const float* __restrict__ w_out,
                                              uint32_t* __restrict__ Wp) {
    int idx = blockIdx.x * 256 + threadIdx.x;      // 0..262143
    int l     = idx >> 16;
    int r     = idx & 65535;
    int kt    = r >> 12;
    int r2    = r & 4095;
    int plane = r2 >> 11;
    int r3    = r2 & 2047;
    int s8    = r3 >> 10;
    int n     = (r3 >> 2) & 255;
    int w     = r3 & 3;
    int kp    = kt * 8 + s8 * 4 + w;               // 0..127
    int klo   = 2 * (kp & ~31) + (kp & 31);
    int khi   = klo + 32;
    const float* Wsrc = (l < 3) ? (w_hid + l * 65536) : w_out;
    float a = Wsrc[klo * 256 + n];
    float b = Wsrc[khi * 256 + n];
    uint32_t ha = f2h(a), hb = f2h(b);
    uint32_t word;
    if (plane == 0) {
        word = ha | (hb << 16);
    } else {
        uint32_t la = f2h(a - h2f(ha));
        uint32_t lb = f2h(b - h2f(hb));
        word = la | (lb << 16);
    }
    Wp[idx] = word;
}

// sA layout (single f16 plane, 32 rows): (kq<<7) + ((m ^ (kq&7))<<2) + (kp&3)
// kp = pair index (logical cols klo(kp), klo(kp)+32), kq = kp>>2, m = row 0..31.
// sA = 4096 words = 16 KB. Final phase reuses the same 16 KB as E (two
// 4-sample halves) -> LDS no longer caps occupancy; regs do (~5 blocks/CU).
//
// Wave tiling: 4 waves, wave w = column group cg (64 cols, two 32-col tiles
// acc[0]/acc[1]); every wave covers ALL 32 rows; col sets DISJOINT across waves.
// Arithmetic: A single f16 plane, B f16 hi+lo -> 4 mfma/tt:
//   acc += A*Bh + A*Bl  (per col-tile)
__global__ __launch_bounds__(THREADS, 5) void divfree_mfma(
    const float* __restrict__ x,
    const uint32_t* __restrict__ Wp,
    const float* __restrict__ w_in,
    const float* __restrict__ b_in,
    const float* __restrict__ b_hid,
    const float* __restrict__ b_out,
    float* __restrict__ out)
{
    __shared__ uint32_t lds[4096];                 // 16 KB
    const int tid  = threadIdx.x;
    const int wave = tid >> 6, lane = tid & 63;
    const int l5 = lane >> 5, ln = lane & 31;
    const int s0 = blockIdx.x * SPB;
    const int cg = wave;                           // column group (64 cols)
    const int n1 = cg * 64 + ln;                   // lower output column
    const int n4v = n1 * 4;                        // B-frag word offset (ct=1: +128)

    // 2-deep software-pipelined B prefetch, slots = tt&1, 2 col-tiles each
    uint4 qh[2][2], ql[2][2];
    #pragma unroll
    for (int c = 0; c < 2; ++c) {
        const uint32_t* Bb = Wp + c * CHUNK_WORDS + l5 * 1024;
        qh[c][0] = *(const uint4*)(Bb + n4v);
        ql[c][0] = *(const uint4*)(Bb + 2048 + n4v);
        qh[c][1] = *(const uint4*)(Bb + n4v + 128);
        ql[c][1] = *(const uint4*)(Bb + 2048 + n4v + 128);
    }

    { // ---- input layer: thread owns row m=tid&31, kq slabs i*8 + (tid>>5) ----
        const int m   = tid & 31;
        const int g   = tid >> 5;                  // 0..7
        const int s   = m >> 2;
        const int row = m & 3;
        const float x0 = x[(s0 + s) * 3 + 0];
        const float x1 = x[(s0 + s) * 3 + 1];
        const float x2 = x[(s0 + s) * 3 + 2];
        #pragma unroll
        for (int i = 0; i < 4; ++i) {
            const int kq = i * 8 + g;              // 0..31
            // slab kq = pairs kq*4..kq*4+3 = logical k's {kA..kA+3, kA+32..kA+35}
            const int kA = ((kq >> 3) << 6) + ((kq & 7) << 2);
            float4 w0A = *(const float4*)&w_in[kA];
            float4 w1A = *(const float4*)&w_in[256 + kA];
            float4 w2A = *(const float4*)&w_in[512 + kA];
            float4 bbA = *(const float4*)&b_in[kA];
            float4 w0B = *(const float4*)&w_in[kA + 32];
            float4 w1B = *(const float4*)&w_in[256 + kA + 32];
            float4 w2B = *(const float4*)&w_in[512 + kA + 32];
            float4 bbB = *(const float4*)&b_in[kA + 32];
            float W0A[4] = {w0A.x, w0A.y, w0A.z, w0A.w};
            float W1A[4] = {w1A.x, w1A.y, w1A.z, w1A.w};
            float W2A[4] = {w2A.x, w2A.y, w2A.z, w2A.w};
            float BBA[4] = {bbA.x, bbA.y, bbA.z, bbA.w};
            float W0B[4] = {w0B.x, w0B.y, w0B.z, w0B.w};
            float W1B[4] = {w1B.x, w1B.y, w1B.z, w1B.w};
            float W2B[4] = {w2B.x, w2B.y, w2B.z, w2B.w};
            float BBB[4] = {bbB.x, bbB.y, bbB.z, bbB.w};
            uint32_t hw[4];
            #pragma unroll
            for (int e = 0; e < 4; ++e) {
                float preA = x0 * W0A[e] + x1 * W1A[e] + x2 * W2A[e] + BBA[e];
                float sigA = 1.f / (1.f + __expf(-preA));
                float spA  = sigA * (1.f + preA * (1.f - sigA));
                float wsA  = (row == 1) ? W0A[e] : (row == 2) ? W1A[e] : W2A[e];
                float vA   = (row == 0) ? preA * sigA : spA * wsA;
                float preB = x0 * W0B[e] + x1 * W1B[e] + x2 * W2B[e] + BBB[e];
                float sigB = 1.f / (1.f + __expf(-preB));
                float spB  = sigB * (1.f + preB * (1.f - sigB));
                float wsB  = (row == 1) ? W0B[e] : (row == 2) ? W1B[e] : W2B[e];
                float vB   = (row == 0) ? preB * sigB : spB * wsB;
                hw[e] = packh(vA, vB);
            }
            const int base = (kq << 7) + ((m ^ (kq & 7)) << 2);
            *(uint4*)&lds[base] = *(uint4*)hw;
        }
    }
    __syncthreads();

    // A-frag LDS word bases: slot j = tt&3 (kq = 2*tt+l5 -> kq&7 period 4 in tt).
    int abase[4];
    #pragma unroll
    for (int j = 0; j < 4; ++j) {
        const int kq = 2 * j + l5;
        abase[j] = (kq << 7) + ((ln ^ (kq & 7)) << 2);
    }

    #pragma unroll 1
    for (int l = 0; l < 4; ++l) {
        f32x16 acc[2];
        acc[0] = (f32x16)0.0f;
        acc[1] = (f32x16)0.0f;

        #pragma unroll
        for (int tt = 0; tt < 16; ++tt) {          // fully unrolled K-loop
            const int slot = tt & 1;
            FragH bh0, bl0, bh1, bl1;
            *(uint4*)&bh0.u[0] = qh[slot][0];
            *(uint4*)&bl0.u[0] = ql[slot][0];
            *(uint4*)&bh1.u[0] = qh[slot][1];
            *(uint4*)&bl1.u[0] = ql[slot][1];
            // refill this slot with chunk lin+2 (uniform -> scalar pipe)
            int lin = l * 16 + tt + 2;
            if (lin > NCHUNK_TOT - 1) lin = NCHUNK_TOT - 1;
            const uint32_t* Bb = Wp + lin * CHUNK_WORDS + l5 * 1024;
            qh[slot][0] = *(const uint4*)(Bb + n4v);
            ql[slot][0] = *(const uint4*)(Bb + 2048 + n4v);
            qh[slot][1] = *(const uint4*)(Bb + n4v + 128);
            ql[slot][1] = *(const uint4*)(Bb + 2048 + n4v + 128);

            // A frag: zero per-step address VALU (base reg + immediate)
            const int aw = abase[tt & 3] + (tt >> 2) * 1024;
            FragH a;
            *(uint4*)&a.u[0] = *(const uint4*)&lds[aw];

            __builtin_amdgcn_s_setprio(1);
            acc[0] = __builtin_amdgcn_mfma_f32_32x32x16_f16(a.v, bh0.v, acc[0], 0, 0, 0);
            acc[0] = __builtin_amdgcn_mfma_f32_32x32x16_f16(a.v, bl0.v, acc[0], 0, 0, 0);
            acc[1] = __builtin_amdgcn_mfma_f32_32x32x16_f16(a.v, bh1.v, acc[1], 0, 0, 0);
            acc[1] = __builtin_amdgcn_mfma_f32_32x32x16_f16(a.v, bl1.v, acc[1], 0, 0, 0);
            __builtin_amdgcn_s_setprio(0);
        }

        // hoist bias loads above the barrier (no LDS dependence)
        float bn0 = 0.f, bn1 = 0.f;
        if (l < 3) {
            bn0 = b_hid[l * 256 + n1];
            bn1 = b_hid[l * 256 + n1 + 32];
        }
        __syncthreads();                           // all waves done READING sA(l)

        if (l < 3) {
            // C layout per acc: col = n (lane ln), row = st + 8*rg + 4*l5
            // This lane writes pair p = cg*32+ln = cols (n1, n1+32) for 16 rows.
            const int kq    = cg * 8 + (ln >> 2);  // p>>2 ; kq&7 == ln>>2
            const int xr    = ln >> 2;
            const int wbase = (kq << 7) + (ln & 3);
            #pragma unroll
            for (int rg = 0; rg < 4; ++rg) {
                float v0[4], v1[4];
                {
                    const float pre = acc[0][rg * 4 + 0] + bn0;
                    const float sig = 1.f / (1.f + __expf(-pre));
                    const float sp  = sig * (1.f + pre * (1.f - sig));
                    v0[0] = pre * sig;
                    v0[1] = sp * acc[0][rg * 4 + 1];
                    v0[2] = sp * acc[0][rg * 4 + 2];
                    v0[3] = sp * acc[0][rg * 4 + 3];
                }
                {
                    const float pre = acc[1][rg * 4 + 0] + bn1;
                    const float sig = 1.f / (1.f + __expf(-pre));
                    const float sp  = sig * (1.f + pre * (1.f - sig));
                    v1[0] = pre * sig;
                    v1[1] = sp * acc[1][rg * 4 + 1];
                    v1[2] = sp * acc[1][rg * 4 + 2];
                    v1[3] = sp * acc[1][rg * 4 + 3];
                }
                const int mb = 8 * rg + 4 * l5;
                #pragma unroll
                for (int st = 0; st < 4; ++st) {
                    const int a = wbase + (((mb + st) ^ xr) << 2);
                    lds[a] = packh(v0[st], v1[st]);
                }
            }
            __syncthreads();                       // sA(l+1) visible
        } else {
            // final phase in TWO 4-sample halves so E fits the 16 KB sA space.
            float* E = (float*)lds;
            float4 bo = *(const float4*)&b_out[lane * 4];
            #pragma unroll
            for (int h = 0; h < 2; ++h) {
                if (h) __syncthreads();            // E half0 fully consumed
                // dump raw output-GEMM results for samples 4h..4h+3
                #pragma unroll
                for (int ct = 0; ct < 2; ++ct) {
                    const int n = n1 + ct * 32;
                    #pragma unroll
                    for (int rr = 0; rr < 2; ++rr) {
                        const int rg  = 2 * h + rr;
                        const int smp = 2 * rr + l5;   // local 0..3
                        #pragma unroll
                        for (int st = 0; st < 4; ++st)
                            E[(smp * 4 + st) * 256 + n] = acc[ct][rg * 4 + st];
                    }
                }
                __syncthreads();
                // lane = mixture, wave w -> local sample w
                const float4* E4 = (const float4*)lds;
                const int sl = wave;
                float4 o  = E4[(sl * 4 + 0) * 64 + lane];
                float4 t1 = E4[(sl * 4 + 1) * 64 + lane];
                float4 t2 = E4[(sl * 4 + 2) * 64 + lane];
                float4 t3 = E4[(sl * 4 + 3) * 64 + lane];
                float sm  = o.x + bo.x;
                float oa0 = o.y + bo.y, oa1 = o.z + bo.z, oa2 = o.w + bo.w;
                float ds0 = t1.x, ds1 = t2.x, ds2 = t3.x;
                float mx = wmax(sm);
                float e  = __expf(sm - mx);
                float Z  = wsum(e);
                float T0 = wsum(e * ds0) / Z;
                float T1 = wsum(e * ds1) / Z;
                float T2 = wsum(e * ds2) / Z;
                float g0 =  (ds1 - T1) * oa0 + t2.y + (ds2 - T2) * oa1 + t3.z;
                float g1 = -((ds0 - T0) * oa0 + t1.y) + (ds2 - T2) * oa2 + t3.w;
                float g2 = -((ds0 - T0) * oa1 + t1.z) - ((ds1 - T1) * oa2 + t2.w);
                float u0 = wsum(e * g0) / Z;
                float u1 = wsum(e * g1) / Z;
                float u2 = wsum(e * g2) / Z;
                if (lane == 0) {
                    const int sg = s0 + 4 * h + wave;
                    out[sg * 3 + 0] = u0;
                    out[sg * 3 + 1] = u1;
                    out[sg * 3 + 2] = u2;
                }
            }
        }
    }
}

extern "C" void kernel_launch(void* const* d_in, const int* in_sizes, int n_in,
                              void* d_out, int out_size, void* d_ws, size_t ws_size,
                              hipStream_t stream) {
    const float* x     = (const float*)d_in[0];
    const float* w_in  = (const float*)d_in[1];
    const float* b_in  = (const float*)d_in[2];
    const float* w_hid = (const float*)d_in[3];
    const float* b_hid = (const float*)d_in[4];
    const float* w_out = (const float*)d_in[5];
    const float* b_out = (const float*)d_in[6];
    float* out = (float*)d_out;
    uint32_t* Wp = (uint32_t*)d_ws;                 // 1 MB packed-weight image
    const int N = in_sizes[0] / 3;

    pack_w<<<1024, 256, 0, stream>>>(w_hid, w_out, Wp);
    divfree_mfma<<<N / SPB, THREADS, 0, stream>>>(x, Wp, w_in, b_in, b_hid, b_out, out);
}

// Round 5
// 447.478 us; speedup vs baseline: 1.3018x; 1.3018x over previous
//
#include <hip/hip_runtime.h>
#include <stdint.h>

#define THREADS 256
#define SPB 8                  // samples per block -> 32 A-rows
#define CHUNK_WORDS 4096       // one K=16 W chunk: hi plane 2048 + lo plane 2048 words
#define NCHUNK_TOT 64          // 4 layers x 16 chunks, linearized

typedef _Float16 f16x8 __attribute__((ext_vector_type(8)));
typedef float f32x16 __attribute__((ext_vector_type(16)));

union FragH { uint32_t u[4]; f16x8 v; };

__device__ __forceinline__ uint32_t f2h(float f) {     // RNE f32->f16 bits
    _Float16 h = (_Float16)f;                          // v_cvt_f16_f32 (RNE)
    return (uint32_t)__builtin_bit_cast(uint16_t, h);
}
__device__ __forceinline__ float h2f(uint32_t b) {
    return (float)__builtin_bit_cast(_Float16, (uint16_t)(b & 0xffffu));
}
__device__ __forceinline__ uint32_t packh(float a, float b) {  // f16(a)|f16(b)<<16
    return f2h(a) | (f2h(b) << 16);
}
__device__ __forceinline__ float wsum(float v) {
    #pragma unroll
    for (int off = 32; off > 0; off >>= 1) v += __shfl_xor(v, off, 64);
    return v;
}
__device__ __forceinline__ float wmax(float v) {
    #pragma unroll
    for (int off = 32; off > 0; off >>= 1) v = fmaxf(v, __shfl_xor(v, off, 64));
    return v;
}

// ---- pre-kernel: pack W into planar hi/lo f16 k-pair chunk images ----
// word idx = l*65536 + kt*4096 + plane*2048 + s8*1024 + n*4 + w
// PAIR PERMUTATION: pair index kp = kt*8 + s8*4 + w holds logical k's
//   klo(kp) = 2*(kp & ~31) + (kp & 31)   and   khi = klo + 32
// so a lane's two output columns (n, n+32) form one f16 k-pair IN-LANE.
// plane0 = f16 RNE of w; plane1 = f16 of residual (B gets ~22 effective bits).
__global__ __launch_bounds__(256) void pack_w(const float* __restrict__ w_hid,
                                              const float* __restrict__ w_out,
                                              uint32_t* __restrict__ Wp) {
    int idx = blockIdx.x * 256 + threadIdx.x;      // 0..262143
    int l     = idx >> 16;
    int r     = idx & 65535;
    int kt    = r >> 12;
    int r2    = r & 4095;
    int plane = r2 >> 11;
    int r3    = r2 & 2047;
    int s8    = r3 >> 10;
    int n     = (r3 >> 2) & 255;
    int w     = r3 & 3;
    int kp    = kt * 8 + s8 * 4 + w;               // 0..127
    int klo   = 2 * (kp & ~31) + (kp & 31);
    int khi   = klo + 32;
    const float* Wsrc = (l < 3) ? (w_hid + l * 65536) : w_out;
    float a = Wsrc[klo * 256 + n];
    float b = Wsrc[khi * 256 + n];
    uint32_t ha = f2h(a), hb = f2h(b);
    uint32_t word;
    if (plane == 0) {
        word = ha | (hb << 16);
    } else {
        uint32_t la = f2h(a - h2f(ha));
        uint32_t lb = f2h(b - h2f(hb));
        word = la | (lb << 16);
    }
    Wp[idx] = word;
}

// sA layout (single f16 plane, 32 rows): (kq<<7) + ((m ^ (kq&7))<<2) + (kp&3)
// kp = pair index (logical cols klo(kp), klo(kp)+32), kq = kp>>2, m = row 0..31.
// sA = 4096 words = 16 KB; lds[] is 32 KB so the final phase's fp32 E
// (8 samples x 4 states x 256) overlays the whole buffer. 32 KB -> LDS
// allows 5 blocks/CU; registers target 4 ((256,4): 128-reg budget >= ~110
// demand -> NO SPILL; round 4's (256,5)=102 budget spilled 1.25 GB).
//
// Wave tiling: 4 waves, wave w = column group cg (64 cols, two 32-col tiles
// acc[0]/acc[1]); every wave covers ALL 32 rows; col sets DISJOINT across waves.
// Arithmetic: A single f16 plane, B f16 hi+lo -> 4 mfma/tt:
//   acc += A*Bh + A*Bl  (per col-tile)
__global__ __launch_bounds__(THREADS, 4) void divfree_mfma(
    const float* __restrict__ x,
    const uint32_t* __restrict__ Wp,
    const float* __restrict__ w_in,
    const float* __restrict__ b_in,
    const float* __restrict__ b_hid,
    const float* __restrict__ b_out,
    float* __restrict__ out)
{
    __shared__ uint32_t lds[8192];                 // 32 KB (sA uses first 16 KB)
    const int tid  = threadIdx.x;
    const int wave = tid >> 6, lane = tid & 63;
    const int l5 = lane >> 5, ln = lane & 31;
    const int s0 = blockIdx.x * SPB;
    const int cg = wave;                           // column group (64 cols)
    const int n1 = cg * 64 + ln;                   // lower output column
    const int n4v = n1 * 4;                        // B-frag word offset (ct=1: +128)

    // 2-deep software-pipelined B prefetch, slots = tt&1, 2 col-tiles each
    uint4 qh[2][2], ql[2][2];
    #pragma unroll
    for (int c = 0; c < 2; ++c) {
        const uint32_t* Bb = Wp + c * CHUNK_WORDS + l5 * 1024;
        qh[c][0] = *(const uint4*)(Bb + n4v);
        ql[c][0] = *(const uint4*)(Bb + 2048 + n4v);
        qh[c][1] = *(const uint4*)(Bb + n4v + 128);
        ql[c][1] = *(const uint4*)(Bb + 2048 + n4v + 128);
    }

    { // ---- input layer: thread owns row m=tid&31, kq slabs i*8 + (tid>>5) ----
        const int m   = tid & 31;
        const int g   = tid >> 5;                  // 0..7
        const int s   = m >> 2;
        const int row = m & 3;
        const float x0 = x[(s0 + s) * 3 + 0];
        const float x1 = x[(s0 + s) * 3 + 1];
        const float x2 = x[(s0 + s) * 3 + 2];
        #pragma unroll
        for (int i = 0; i < 4; ++i) {
            const int kq = i * 8 + g;              // 0..31
            // slab kq = pairs kq*4..kq*4+3 = logical k's {kA..kA+3, kA+32..kA+35}
            const int kA = ((kq >> 3) << 6) + ((kq & 7) << 2);
            float4 w0A = *(const float4*)&w_in[kA];
            float4 w1A = *(const float4*)&w_in[256 + kA];
            float4 w2A = *(const float4*)&w_in[512 + kA];
            float4 bbA = *(const float4*)&b_in[kA];
            float4 w0B = *(const float4*)&w_in[kA + 32];
            float4 w1B = *(const float4*)&w_in[256 + kA + 32];
            float4 w2B = *(const float4*)&w_in[512 + kA + 32];
            float4 bbB = *(const float4*)&b_in[kA + 32];
            float W0A[4] = {w0A.x, w0A.y, w0A.z, w0A.w};
            float W1A[4] = {w1A.x, w1A.y, w1A.z, w1A.w};
            float W2A[4] = {w2A.x, w2A.y, w2A.z, w2A.w};
            float BBA[4] = {bbA.x, bbA.y, bbA.z, bbA.w};
            float W0B[4] = {w0B.x, w0B.y, w0B.z, w0B.w};
            float W1B[4] = {w1B.x, w1B.y, w1B.z, w1B.w};
            float W2B[4] = {w2B.x, w2B.y, w2B.z, w2B.w};
            float BBB[4] = {bbB.x, bbB.y, bbB.z, bbB.w};
            uint32_t hw[4];
            #pragma unroll
            for (int e = 0; e < 4; ++e) {
                float preA = x0 * W0A[e] + x1 * W1A[e] + x2 * W2A[e] + BBA[e];
                float sigA = 1.f / (1.f + __expf(-preA));
                float spA  = sigA * (1.f + preA * (1.f - sigA));
                float wsA  = (row == 1) ? W0A[e] : (row == 2) ? W1A[e] : W2A[e];
                float vA   = (row == 0) ? preA * sigA : spA * wsA;
                float preB = x0 * W0B[e] + x1 * W1B[e] + x2 * W2B[e] + BBB[e];
                float sigB = 1.f / (1.f + __expf(-preB));
                float spB  = sigB * (1.f + preB * (1.f - sigB));
                float wsB  = (row == 1) ? W0B[e] : (row == 2) ? W1B[e] : W2B[e];
                float vB   = (row == 0) ? preB * sigB : spB * wsB;
                hw[e] = packh(vA, vB);
            }
            const int base = (kq << 7) + ((m ^ (kq & 7)) << 2);
            *(uint4*)&lds[base] = *(uint4*)hw;
        }
    }
    __syncthreads();

    // A-frag LDS word bases: slot j = tt&3 (kq = 2*tt+l5 -> kq&7 period 4 in tt).
    int abase[4];
    #pragma unroll
    for (int j = 0; j < 4; ++j) {
        const int kq = 2 * j + l5;
        abase[j] = (kq << 7) + ((ln ^ (kq & 7)) << 2);
    }

    #pragma unroll 1
    for (int l = 0; l < 4; ++l) {
        f32x16 acc[2];
        acc[0] = (f32x16)0.0f;
        acc[1] = (f32x16)0.0f;

        #pragma unroll
        for (int tt = 0; tt < 16; ++tt) {          // fully unrolled K-loop
            const int slot = tt & 1;
            FragH bh0, bl0, bh1, bl1;
            *(uint4*)&bh0.u[0] = qh[slot][0];
            *(uint4*)&bl0.u[0] = ql[slot][0];
            *(uint4*)&bh1.u[0] = qh[slot][1];
            *(uint4*)&bl1.u[0] = ql[slot][1];
            // refill this slot with chunk lin+2 (uniform -> scalar pipe)
            int lin = l * 16 + tt + 2;
            if (lin > NCHUNK_TOT - 1) lin = NCHUNK_TOT - 1;
            const uint32_t* Bb = Wp + lin * CHUNK_WORDS + l5 * 1024;
            qh[slot][0] = *(const uint4*)(Bb + n4v);
            ql[slot][0] = *(const uint4*)(Bb + 2048 + n4v);
            qh[slot][1] = *(const uint4*)(Bb + n4v + 128);
            ql[slot][1] = *(const uint4*)(Bb + 2048 + n4v + 128);

            // A frag: zero per-step address VALU (base reg + immediate)
            const int aw = abase[tt & 3] + (tt >> 2) * 1024;
            FragH a;
            *(uint4*)&a.u[0] = *(const uint4*)&lds[aw];

            __builtin_amdgcn_s_setprio(1);
            acc[0] = __builtin_amdgcn_mfma_f32_32x32x16_f16(a.v, bh0.v, acc[0], 0, 0, 0);
            acc[0] = __builtin_amdgcn_mfma_f32_32x32x16_f16(a.v, bl0.v, acc[0], 0, 0, 0);
            acc[1] = __builtin_amdgcn_mfma_f32_32x32x16_f16(a.v, bh1.v, acc[1], 0, 0, 0);
            acc[1] = __builtin_amdgcn_mfma_f32_32x32x16_f16(a.v, bl1.v, acc[1], 0, 0, 0);
            __builtin_amdgcn_s_setprio(0);
        }

        // hoist bias loads above the barrier (no LDS dependence)
        float bn0 = 0.f, bn1 = 0.f;
        if (l < 3) {
            bn0 = b_hid[l * 256 + n1];
            bn1 = b_hid[l * 256 + n1 + 32];
        }
        __syncthreads();                           // all waves done READING sA(l)

        if (l < 3) {
            // C layout per acc: col = n (lane ln), row = st + 8*rg + 4*l5
            // This lane writes pair p = cg*32+ln = cols (n1, n1+32) for 16 rows.
            const int kq    = cg * 8 + (ln >> 2);  // p>>2 ; kq&7 == ln>>2
            const int xr    = ln >> 2;
            const int wbase = (kq << 7) + (ln & 3);
            #pragma unroll
            for (int rg = 0; rg < 4; ++rg) {
                float v0[4], v1[4];
                {
                    const float pre = acc[0][rg * 4 + 0] + bn0;
                    const float sig = 1.f / (1.f + __expf(-pre));
                    const float sp  = sig * (1.f + pre * (1.f - sig));
                    v0[0] = pre * sig;
                    v0[1] = sp * acc[0][rg * 4 + 1];
                    v0[2] = sp * acc[0][rg * 4 + 2];
                    v0[3] = sp * acc[0][rg * 4 + 3];
                }
                {
                    const float pre = acc[1][rg * 4 + 0] + bn1;
                    const float sig = 1.f / (1.f + __expf(-pre));
                    const float sp  = sig * (1.f + pre * (1.f - sig));
                    v1[0] = pre * sig;
                    v1[1] = sp * acc[1][rg * 4 + 1];
                    v1[2] = sp * acc[1][rg * 4 + 2];
                    v1[3] = sp * acc[1][rg * 4 + 3];
                }
                const int mb = 8 * rg + 4 * l5;
                #pragma unroll
                for (int st = 0; st < 4; ++st) {
                    const int a = wbase + (((mb + st) ^ xr) << 2);
                    lds[a] = packh(v0[st], v1[st]);
                }
            }
            __syncthreads();                       // sA(l+1) visible
        } else {
            // dump raw output-GEMM results to E[smp][state][n] fp32 (32 KB,
            // overlays the whole lds[] -- sA is dead here)
            float* E = (float*)lds;
            #pragma unroll
            for (int ct = 0; ct < 2; ++ct) {
                const int n = n1 + ct * 32;
                #pragma unroll
                for (int rg = 0; rg < 4; ++rg) {
                    const int smp = 2 * rg + l5;
                    #pragma unroll
                    for (int st = 0; st < 4; ++st)
                        E[(smp * 4 + st) * 256 + n] = acc[ct][rg * 4 + st];
                }
            }
            __syncthreads();
            // final phase: lane = mixture, wave w -> samples 2w..2w+1
            const float4* E4 = (const float4*)lds;
            float4 bo = *(const float4*)&b_out[lane * 4];
            #pragma unroll
            for (int g = 0; g < 2; ++g) {
                const int sl = wave * 2 + g;       // 0..7
                float4 o  = E4[(sl * 4 + 0) * 64 + lane];
                float4 t1 = E4[(sl * 4 + 1) * 64 + lane];
                float4 t2 = E4[(sl * 4 + 2) * 64 + lane];
                float4 t3 = E4[(sl * 4 + 3) * 64 + lane];
                float sm  = o.x + bo.x;
                float oa0 = o.y + bo.y, oa1 = o.z + bo.z, oa2 = o.w + bo.w;
                float ds0 = t1.x, ds1 = t2.x, ds2 = t3.x;
                float mx = wmax(sm);
                float e  = __expf(sm - mx);
                float Z  = wsum(e);
                float T0 = wsum(e * ds0) / Z;
                float T1 = wsum(e * ds1) / Z;
                float T2 = wsum(e * ds2) / Z;
                float g0 =  (ds1 - T1) * oa0 + t2.y + (ds2 - T2) * oa1 + t3.z;
                float g1 = -((ds0 - T0) * oa0 + t1.y) + (ds2 - T2) * oa2 + t3.w;
                float g2 = -((ds0 - T0) * oa1 + t1.z) - ((ds1 - T1) * oa2 + t2.w);
                float u0 = wsum(e * g0) / Z;
                float u1 = wsum(e * g1) / Z;
                float u2 = wsum(e * g2) / Z;
                if (lane == 0) {
                    const int sg = s0 + sl;
                    out[sg * 3 + 0] = u0;
                    out[sg * 3 + 1] = u1;
                    out[sg * 3 + 2] = u2;
                }
            }
        }
    }
}

extern "C" void kernel_launch(void* const* d_in, const int* in_sizes, int n_in,
                              void* d_out, int out_size, void* d_ws, size_t ws_size,
                              hipStream_t stream) {
    const float* x     = (const float*)d_in[0];
    const float* w_in  = (const float*)d_in[1];
    const float* b_in  = (const float*)d_in[2];
    const float* w_hid = (const float*)d_in[3];
    const float* b_hid = (const float*)d_in[4];
    const float* w_out = (const float*)d_in[5];
    const float* b_out = (const float*)d_in[6];
    float* out = (float*)d_out;
    uint32_t* Wp = (uint32_t*)d_ws;                 // 1 MB packed-weight image
    const int N = in_sizes[0] / 3;

    pack_w<<<1024, 256, 0, stream>>>(w_hid, w_out, Wp);
    divfree_mfma<<<N / SPB, THREADS, 0, stream>>>(x, Wp, w_in, b_in, b_hid, b_out, out);
}

// Round 6
// 425.161 us; speedup vs baseline: 1.3701x; 1.0525x over previous
//
#include <hip/hip_runtime.h>
#include <stdint.h>

#define THREADS 256
#define SPB 8                  // samples per block -> 32 A-rows
#define CHUNK_WORDS 4096       // one K=16 W chunk: hi plane 2048 + lo plane 2048 words
#define NCHUNK_TOT 64          // 4 layers x 16 chunks, linearized
#define PP 4096                // ping-pong plane stride in words (16 KB)

typedef _Float16 f16x8 __attribute__((ext_vector_type(8)));
typedef float f32x16 __attribute__((ext_vector_type(16)));

union FragH { uint32_t u[4]; f16x8 v; };

__device__ __forceinline__ uint32_t f2h(float f) {     // RNE f32->f16 bits
    _Float16 h = (_Float16)f;                          // v_cvt_f16_f32 (RNE)
    return (uint32_t)__builtin_bit_cast(uint16_t, h);
}
__device__ __forceinline__ float h2f(uint32_t b) {
    return (float)__builtin_bit_cast(_Float16, (uint16_t)(b & 0xffffu));
}
__device__ __forceinline__ uint32_t packh(float a, float b) {  // f16(a)|f16(b)<<16
    return f2h(a) | (f2h(b) << 16);
}
__device__ __forceinline__ float frcp(float x) {       // v_rcp_f32 (~1 ulp, fine vs 2e-4 floor)
    return __builtin_amdgcn_rcpf(x);
}
__device__ __forceinline__ float wsum(float v) {
    #pragma unroll
    for (int off = 32; off > 0; off >>= 1) v += __shfl_xor(v, off, 64);
    return v;
}
__device__ __forceinline__ float wmax(float v) {
    #pragma unroll
    for (int off = 32; off > 0; off >>= 1) v = fmaxf(v, __shfl_xor(v, off, 64));
    return v;
}
// MFMA with B taken straight from the prefetch ring (no union round-trip;
// avoids forced reg copies across the WAR with the ring refill)
__device__ __forceinline__ f32x16 mfma16(f16x8 a, uint4 b, f32x16 c) {
    return __builtin_amdgcn_mfma_f32_32x32x16_f16(a, __builtin_bit_cast(f16x8, b), c, 0, 0, 0);
}

// ---- pre-kernel: pack W into planar hi/lo f16 k-pair chunk images ----
// word idx = l*65536 + kt*4096 + plane*2048 + s8*1024 + n*4 + w
// PAIR PERMUTATION: pair index kp = kt*8 + s8*4 + w holds logical k's
//   klo(kp) = 2*(kp & ~31) + (kp & 31)   and   khi = klo + 32
// so a lane's two output columns (n, n+32) form one f16 k-pair IN-LANE.
// plane0 = f16 RNE of w; plane1 = f16 of residual (B gets ~22 effective bits).
__global__ __launch_bounds__(256) void pack_w(const float* __restrict__ w_hid,
                                              const float* __restrict__ w_out,
                                              uint32_t* __restrict__ Wp) {
    int idx = blockIdx.x * 256 + threadIdx.x;      // 0..262143
    int l     = idx >> 16;
    int r     = idx & 65535;
    int kt    = r >> 12;
    int r2    = r & 4095;
    int plane = r2 >> 11;
    int r3    = r2 & 2047;
    int s8    = r3 >> 10;
    int n     = (r3 >> 2) & 255;
    int w     = r3 & 3;
    int kp    = kt * 8 + s8 * 4 + w;               // 0..127
    int klo   = 2 * (kp & ~31) + (kp & 31);
    int khi   = klo + 32;
    const float* Wsrc = (l < 3) ? (w_hid + l * 65536) : w_out;
    float a = Wsrc[klo * 256 + n];
    float b = Wsrc[khi * 256 + n];
    uint32_t ha = f2h(a), hb = f2h(b);
    uint32_t word;
    if (plane == 0) {
        word = ha | (hb << 16);
    } else {
        uint32_t la = f2h(a - h2f(ha));
        uint32_t lb = f2h(b - h2f(hb));
        word = la | (lb << 16);
    }
    Wp[idx] = word;
}

// sA layout (single f16 plane, 32 rows): (kq<<7) + ((m ^ (kq&7))<<2) + (kp&3)
// kp = pair index (logical cols klo(kp), klo(kp)+32), kq = kp>>2, m = row 0..31.
// PING-PONG: two 16 KB sA planes at word offsets 0 / PP. Layer l READS plane
// (l&1) and its epilogue WRITES plane ((l+1)&1) -> no pre-epilogue barrier:
// one wave's epilogue VALU overlaps other waves' K-loop MFMA. Safety: plane
// (l+1)&1's last readers were layer l-1's K-loop, which completed before
// layer l-1's end barrier (reads precede each wave's own barrier).
// Final phase's fp32 E (8x4x256) overlays the full 32 KB (both planes dead
// after a pre-dump barrier).
//
// Wave tiling: 4 waves, wave w = column group cg (64 cols, two 32-col tiles
// acc[0]/acc[1]); every wave covers ALL 32 rows; col sets DISJOINT across waves.
// Arithmetic: A single f16 plane, B f16 hi+lo -> 4 mfma/tt.
__global__ __launch_bounds__(THREADS, 4) void divfree_mfma(
    const float* __restrict__ x,
    const uint32_t* __restrict__ Wp,
    const float* __restrict__ w_in,
    const float* __restrict__ b_in,
    const float* __restrict__ b_hid,
    const float* __restrict__ b_out,
    float* __restrict__ out)
{
    __shared__ uint32_t lds[8192];                 // 32 KB = 2 ping-pong planes
    const int tid  = threadIdx.x;
    const int wave = tid >> 6, lane = tid & 63;
    const int l5 = lane >> 5, ln = lane & 31;
    const int s0 = blockIdx.x * SPB;
    const int cg = wave;                           // column group (64 cols)
    const int n1 = cg * 64 + ln;                   // lower output column
    const int n4v = n1 * 4;                        // B-frag word offset (ct=1: +128)

    // 2-deep software-pipelined B prefetch, slots = tt&1, 2 col-tiles each
    uint4 qh[2][2], ql[2][2];
    #pragma unroll
    for (int c = 0; c < 2; ++c) {
        const uint32_t* Bb = Wp + c * CHUNK_WORDS + l5 * 1024;
        qh[c][0] = *(const uint4*)(Bb + n4v);
        ql[c][0] = *(const uint4*)(Bb + 2048 + n4v);
        qh[c][1] = *(const uint4*)(Bb + n4v + 128);
        ql[c][1] = *(const uint4*)(Bb + 2048 + n4v + 128);
    }

    { // ---- input layer: thread owns row m=tid&31, kq slabs i*8 + (tid>>5) ----
        const int m   = tid & 31;
        const int g   = tid >> 5;                  // 0..7
        const int s   = m >> 2;
        const int row = m & 3;
        const float x0 = x[(s0 + s) * 3 + 0];
        const float x1 = x[(s0 + s) * 3 + 1];
        const float x2 = x[(s0 + s) * 3 + 2];
        #pragma unroll
        for (int i = 0; i < 4; ++i) {
            const int kq = i * 8 + g;              // 0..31
            // slab kq = pairs kq*4..kq*4+3 = logical k's {kA..kA+3, kA+32..kA+35}
            const int kA = ((kq >> 3) << 6) + ((kq & 7) << 2);
            float4 w0A = *(const float4*)&w_in[kA];
            float4 w1A = *(const float4*)&w_in[256 + kA];
            float4 w2A = *(const float4*)&w_in[512 + kA];
            float4 bbA = *(const float4*)&b_in[kA];
            float4 w0B = *(const float4*)&w_in[kA + 32];
            float4 w1B = *(const float4*)&w_in[256 + kA + 32];
            float4 w2B = *(const float4*)&w_in[512 + kA + 32];
            float4 bbB = *(const float4*)&b_in[kA + 32];
            float W0A[4] = {w0A.x, w0A.y, w0A.z, w0A.w};
            float W1A[4] = {w1A.x, w1A.y, w1A.z, w1A.w};
            float W2A[4] = {w2A.x, w2A.y, w2A.z, w2A.w};
            float BBA[4] = {bbA.x, bbA.y, bbA.z, bbA.w};
            float W0B[4] = {w0B.x, w0B.y, w0B.z, w0B.w};
            float W1B[4] = {w1B.x, w1B.y, w1B.z, w1B.w};
            float W2B[4] = {w2B.x, w2B.y, w2B.z, w2B.w};
            float BBB[4] = {bbB.x, bbB.y, bbB.z, bbB.w};
            uint32_t hw[4];
            #pragma unroll
            for (int e = 0; e < 4; ++e) {
                float preA = x0 * W0A[e] + x1 * W1A[e] + x2 * W2A[e] + BBA[e];
                float sigA = frcp(1.f + __expf(-preA));
                float spA  = sigA * (1.f + preA * (1.f - sigA));
                float wsA  = (row == 1) ? W0A[e] : (row == 2) ? W1A[e] : W2A[e];
                float vA   = (row == 0) ? preA * sigA : spA * wsA;
                float preB = x0 * W0B[e] + x1 * W1B[e] + x2 * W2B[e] + BBB[e];
                float sigB = frcp(1.f + __expf(-preB));
                float spB  = sigB * (1.f + preB * (1.f - sigB));
                float wsB  = (row == 1) ? W0B[e] : (row == 2) ? W1B[e] : W2B[e];
                float vB   = (row == 0) ? preB * sigB : spB * wsB;
                hw[e] = packh(vA, vB);
            }
            const int base = (kq << 7) + ((m ^ (kq & 7)) << 2);
            *(uint4*)&lds[base] = *(uint4*)hw;     // plane 0
        }
    }
    __syncthreads();

    // A-frag LDS word bases: slot j = tt&3 (kq = 2*tt+l5 -> kq&7 period 4 in tt).
    int abase[4];
    #pragma unroll
    for (int j = 0; j < 4; ++j) {
        const int kq = 2 * j + l5;
        abase[j] = (kq << 7) + ((ln ^ (kq & 7)) << 2);
    }

    #pragma unroll 1
    for (int l = 0; l < 4; ++l) {
        const int rdoff = (l & 1) ? PP : 0;        // read plane
        const int wroff = (l & 1) ? 0 : PP;        // write plane (epilogue)
        f32x16 acc[2];
        acc[0] = (f32x16)0.0f;
        acc[1] = (f32x16)0.0f;

        #pragma unroll
        for (int tt = 0; tt < 16; ++tt) {          // fully unrolled K-loop
            const int slot = tt & 1;
            // A frag: zero per-step address VALU (base reg + immediate)
            const int aw = rdoff + abase[tt & 3] + (tt >> 2) * 1024;
            FragH a;
            *(uint4*)&a.u[0] = *(const uint4*)&lds[aw];

            // MFMA FIRST, straight from the ring (WAR with refill below;
            // no copies needed -- MFMA reads registers at issue)
            __builtin_amdgcn_s_setprio(1);
            acc[0] = mfma16(a.v, qh[slot][0], acc[0]);
            acc[0] = mfma16(a.v, ql[slot][0], acc[0]);
            acc[1] = mfma16(a.v, qh[slot][1], acc[1]);
            acc[1] = mfma16(a.v, ql[slot][1], acc[1]);
            __builtin_amdgcn_s_setprio(0);

            // refill this slot with chunk lin+2 (uniform -> scalar pipe)
            int lin = l * 16 + tt + 2;
            if (lin > NCHUNK_TOT - 1) lin = NCHUNK_TOT - 1;
            const uint32_t* Bb = Wp + lin * CHUNK_WORDS + l5 * 1024;
            qh[slot][0] = *(const uint4*)(Bb + n4v);
            ql[slot][0] = *(const uint4*)(Bb + 2048 + n4v);
            qh[slot][1] = *(const uint4*)(Bb + n4v + 128);
            ql[slot][1] = *(const uint4*)(Bb + 2048 + n4v + 128);
        }

        if (l < 3) {
            // bias loads (global, no LDS dependence)
            const float bn0 = b_hid[l * 256 + n1];
            const float bn1 = b_hid[l * 256 + n1 + 32];
            // NO barrier here: epilogue writes the OTHER plane (wroff).
            // C layout per acc: col = n (lane ln), row = st + 8*rg + 4*l5
            // This lane writes pair p = cg*32+ln = cols (n1, n1+32) for 16 rows.
            const int kq    = cg * 8 + (ln >> 2);  // p>>2 ; kq&7 == ln>>2
            const int xr    = ln >> 2;
            const int wbase = wroff + (kq << 7) + (ln & 3);
            #pragma unroll
            for (int rg = 0; rg < 4; ++rg) {
                float v0[4], v1[4];
                {
                    const float pre = acc[0][rg * 4 + 0] + bn0;
                    const float sig = frcp(1.f + __expf(-pre));
                    const float sp  = sig * (1.f + pre * (1.f - sig));
                    v0[0] = pre * sig;
                    v0[1] = sp * acc[0][rg * 4 + 1];
                    v0[2] = sp * acc[0][rg * 4 + 2];
                    v0[3] = sp * acc[0][rg * 4 + 3];
                }
                {
                    const float pre = acc[1][rg * 4 + 0] + bn1;
                    const float sig = frcp(1.f + __expf(-pre));
                    const float sp  = sig * (1.f + pre * (1.f - sig));
                    v1[0] = pre * sig;
                    v1[1] = sp * acc[1][rg * 4 + 1];
                    v1[2] = sp * acc[1][rg * 4 + 2];
                    v1[3] = sp * acc[1][rg * 4 + 3];
                }
                const int mb = 8 * rg + 4 * l5;
                #pragma unroll
                for (int st = 0; st < 4; ++st) {
                    const int a = wbase + (((mb + st) ^ xr) << 2);
                    lds[a] = packh(v0[st], v1[st]);
                }
            }
            __syncthreads();                       // sA(l+1) visible to all
        } else {
            __syncthreads();                       // all waves done READING plane 1
            // dump raw output-GEMM results to E[smp][state][n] fp32 (32 KB,
            // overlays both planes -- sA is dead here)
            float* E = (float*)lds;
            #pragma unroll
            for (int ct = 0; ct < 2; ++ct) {
                const int n = n1 + ct * 32;
                #pragma unroll
                for (int rg = 0; rg < 4; ++rg) {
                    const int smp = 2 * rg + l5;
                    #pragma unroll
                    for (int st = 0; st < 4; ++st)
                        E[(smp * 4 + st) * 256 + n] = acc[ct][rg * 4 + st];
                }
            }
            __syncthreads();
            // final phase: lane = mixture, wave w -> samples 2w..2w+1
            const float4* E4 = (const float4*)lds;
            float4 bo = *(const float4*)&b_out[lane * 4];
            #pragma unroll
            for (int g = 0; g < 2; ++g) {
                const int sl = wave * 2 + g;       // 0..7
                float4 o  = E4[(sl * 4 + 0) * 64 + lane];
                float4 t1 = E4[(sl * 4 + 1) * 64 + lane];
                float4 t2 = E4[(sl * 4 + 2) * 64 + lane];
                float4 t3 = E4[(sl * 4 + 3) * 64 + lane];
                float sm  = o.x + bo.x;
                float oa0 = o.y + bo.y, oa1 = o.z + bo.z, oa2 = o.w + bo.w;
                float ds0 = t1.x, ds1 = t2.x, ds2 = t3.x;
                float mx = wmax(sm);
                float e  = __expf(sm - mx);
                float Z  = wsum(e);
                float rZ = frcp(Z);
                float T0 = wsum(e * ds0) * rZ;
                float T1 = wsum(e * ds1) * rZ;
                float T2 = wsum(e * ds2) * rZ;
                float g0 =  (ds1 - T1) * oa0 + t2.y + (ds2 - T2) * oa1 + t3.z;
                float g1 = -((ds0 - T0) * oa0 + t1.y) + (ds2 - T2) * oa2 + t3.w;
                float g2 = -((ds0 - T0) * oa1 + t1.z) - ((ds1 - T1) * oa2 + t2.w);
                float u0 = wsum(e * g0) * rZ;
                float u1 = wsum(e * g1) * rZ;
                float u2 = wsum(e * g2) * rZ;
                if (lane == 0) {
                    const int sg = s0 + sl;
                    out[sg * 3 + 0] = u0;
                    out[sg * 3 + 1] = u1;
                    out[sg * 3 + 2] = u2;
                }
            }
        }
    }
}

extern "C" void kernel_launch(void* const* d_in, const int* in_sizes, int n_in,
                              void* d_out, int out_size, void* d_ws, size_t ws_size,
                              hipStream_t stream) {
    const float* x     = (const float*)d_in[0];
    const float* w_in  = (const float*)d_in[1];
    const float* b_in  = (const float*)d_in[2];
    const float* w_hid = (const float*)d_in[3];
    const float* b_hid = (const float*)d_in[4];
    const float* w_out = (const float*)d_in[5];
    const float* b_out = (const float*)d_in[6];
    float* out = (float*)d_out;
    uint32_t* Wp = (uint32_t*)d_ws;                 // 1 MB packed-weight image
    const int N = in_sizes[0] / 3;

    pack_w<<<1024, 256, 0, stream>>>(w_hid, w_out, Wp);
    divfree_mfma<<<N / SPB, THREADS, 0, stream>>>(x, Wp, w_in, b_in, b_hid, b_out, out);
}

// Round 7
// 277.674 us; speedup vs baseline: 2.0979x; 1.5311x over previous
//
#include <hip/hip_runtime.h>
#include <stdint.h>

#define THREADS 256
#define SPB 8                  // samples per block -> 32 A-rows
#define CHUNK_WORDS 4096       // one K=16 W chunk: hi plane 2048 + lo plane 2048 words
#define NCHUNK_TOT 64          // 4 layers x 16 chunks, linearized
#define PP 4096                // ping-pong plane stride in words (16 KB)

typedef _Float16 f16x8 __attribute__((ext_vector_type(8)));
typedef float f32x16 __attribute__((ext_vector_type(16)));

union FragH { uint32_t u[4]; f16x8 v; };

__device__ __forceinline__ uint32_t f2h(float f) {     // RNE f32->f16 bits
    _Float16 h = (_Float16)f;                          // v_cvt_f16_f32 (RNE)
    return (uint32_t)__builtin_bit_cast(uint16_t, h);
}
__device__ __forceinline__ float h2f(uint32_t b) {
    return (float)__builtin_bit_cast(_Float16, (uint16_t)(b & 0xffffu));
}
__device__ __forceinline__ uint32_t packh(float a, float b) {  // f16(a)|f16(b)<<16
    return f2h(a) | (f2h(b) << 16);
}
__device__ __forceinline__ float frcp(float x) {       // v_rcp_f32 (~1 ulp, fine vs 2e-4 floor)
    return __builtin_amdgcn_rcpf(x);
}
__device__ __forceinline__ float wsum(float v) {
    #pragma unroll
    for (int off = 32; off > 0; off >>= 1) v += __shfl_xor(v, off, 64);
    return v;
}
__device__ __forceinline__ float wmax(float v) {
    #pragma unroll
    for (int off = 32; off > 0; off >>= 1) v = fmaxf(v, __shfl_xor(v, off, 64));
    return v;
}
// MFMA with B taken straight from the prefetch ring (no union round-trip;
// avoids forced reg copies across the WAR with the ring refill)
__device__ __forceinline__ f32x16 mfma16(f16x8 a, uint4 b, f32x16 c) {
    return __builtin_amdgcn_mfma_f32_32x32x16_f16(a, __builtin_bit_cast(f16x8, b), c, 0, 0, 0);
}

// ---- pre-kernel: pack W into planar hi/lo f16 k-pair chunk images ----
// word idx = l*65536 + kt*4096 + plane*2048 + s8*1024 + n*4 + w
// PAIR PERMUTATION: pair index kp = kt*8 + s8*4 + w holds logical k's
//   klo(kp) = 2*(kp & ~31) + (kp & 31)   and   khi = klo + 32
// so a lane's two output columns (n, n+32) form one f16 k-pair IN-LANE.
// plane0 = f16 RNE of w; plane1 = residual (UNUSED by the main kernel as of
// this round: A-f16-only left absmax bit-identical at 2^-12 across 3 configs,
// evidence operand rounding ~1e-4 is invisible -> B hi-only, 2 mfma/tt).
__global__ __launch_bounds__(256) void pack_w(const float* __restrict__ w_hid,
                                              const float* __restrict__ w_out,
                                              uint32_t* __restrict__ Wp) {
    int idx = blockIdx.x * 256 + threadIdx.x;      // 0..262143
    int l     = idx >> 16;
    int r     = idx & 65535;
    int kt    = r >> 12;
    int r2    = r & 4095;
    int plane = r2 >> 11;
    int r3    = r2 & 2047;
    int s8    = r3 >> 10;
    int n     = (r3 >> 2) & 255;
    int w     = r3 & 3;
    int kp    = kt * 8 + s8 * 4 + w;               // 0..127
    int klo   = 2 * (kp & ~31) + (kp & 31);
    int khi   = klo + 32;
    const float* Wsrc = (l < 3) ? (w_hid + l * 65536) : w_out;
    float a = Wsrc[klo * 256 + n];
    float b = Wsrc[khi * 256 + n];
    uint32_t ha = f2h(a), hb = f2h(b);
    uint32_t word;
    if (plane == 0) {
        word = ha | (hb << 16);
    } else {
        uint32_t la = f2h(a - h2f(ha));
        uint32_t lb = f2h(b - h2f(hb));
        word = la | (lb << 16);
    }
    Wp[idx] = word;
}

// sA layout (single f16 plane, 32 rows): (kq<<7) + ((m ^ (kq&7))<<2) + (kp&3)
// kp = pair index (logical cols klo(kp), klo(kp)+32), kq = kp>>2, m = row 0..31.
// PING-PONG: two 16 KB sA planes at word offsets 0 / PP. Layer l READS plane
// (l&1) and its epilogue WRITES plane ((l+1)&1) -> no pre-epilogue barrier.
// Final phase's fp32 E (8x4x256) overlays the full 32 KB.
//
// Wave tiling: 4 waves, wave w = column group cg (64 cols, two 32-col tiles
// acc[0]/acc[1]); every wave covers ALL 32 rows; col sets DISJOINT across waves.
// Arithmetic: A f16, B f16 hi-only -> 2 mfma/tt (one per col-tile).
// B ring: 4-deep (slot = tt&3, refill lin = l*16+tt+4; 16%4==0 keeps the
// slot<->chunk mapping consistent across layer boundaries), 2 loads/tt.
__global__ __launch_bounds__(THREADS, 4) void divfree_mfma(
    const float* __restrict__ x,
    const uint32_t* __restrict__ Wp,
    const float* __restrict__ w_in,
    const float* __restrict__ b_in,
    const float* __restrict__ b_hid,
    const float* __restrict__ b_out,
    float* __restrict__ out)
{
    __shared__ uint32_t lds[8192];                 // 32 KB = 2 ping-pong planes
    const int tid  = threadIdx.x;
    const int wave = tid >> 6, lane = tid & 63;
    const int l5 = lane >> 5, ln = lane & 31;
    const int s0 = blockIdx.x * SPB;
    const int cg = wave;                           // column group (64 cols)
    const int n1 = cg * 64 + ln;                   // lower output column
    const int n4v = n1 * 4;                        // B-frag word offset (ct=1: +128)

    // 4-deep software-pipelined B prefetch (hi plane only), 2 col-tiles/slot
    uint4 qh[4][2];
    #pragma unroll
    for (int c = 0; c < 4; ++c) {
        const uint32_t* Bb = Wp + c * CHUNK_WORDS + l5 * 1024;
        qh[c][0] = *(const uint4*)(Bb + n4v);
        qh[c][1] = *(const uint4*)(Bb + n4v + 128);
    }

    { // ---- input layer: thread owns row m=tid&31, kq slabs i*8 + (tid>>5) ----
        const int m   = tid & 31;
        const int g   = tid >> 5;                  // 0..7
        const int s   = m >> 2;
        const int row = m & 3;
        const float x0 = x[(s0 + s) * 3 + 0];
        const float x1 = x[(s0 + s) * 3 + 1];
        const float x2 = x[(s0 + s) * 3 + 2];
        #pragma unroll
        for (int i = 0; i < 4; ++i) {
            const int kq = i * 8 + g;              // 0..31
            // slab kq = pairs kq*4..kq*4+3 = logical k's {kA..kA+3, kA+32..kA+35}
            const int kA = ((kq >> 3) << 6) + ((kq & 7) << 2);
            float4 w0A = *(const float4*)&w_in[kA];
            float4 w1A = *(const float4*)&w_in[256 + kA];
            float4 w2A = *(const float4*)&w_in[512 + kA];
            float4 bbA = *(const float4*)&b_in[kA];
            float4 w0B = *(const float4*)&w_in[kA + 32];
            float4 w1B = *(const float4*)&w_in[256 + kA + 32];
            float4 w2B = *(const float4*)&w_in[512 + kA + 32];
            float4 bbB = *(const float4*)&b_in[kA + 32];
            float W0A[4] = {w0A.x, w0A.y, w0A.z, w0A.w};
            float W1A[4] = {w1A.x, w1A.y, w1A.z, w1A.w};
            float W2A[4] = {w2A.x, w2A.y, w2A.z, w2A.w};
            float BBA[4] = {bbA.x, bbA.y, bbA.z, bbA.w};
            float W0B[4] = {w0B.x, w0B.y, w0B.z, w0B.w};
            float W1B[4] = {w1B.x, w1B.y, w1B.z, w1B.w};
            float W2B[4] = {w2B.x, w2B.y, w2B.z, w2B.w};
            float BBB[4] = {bbB.x, bbB.y, bbB.z, bbB.w};
            uint32_t hw[4];
            #pragma unroll
            for (int e = 0; e < 4; ++e) {
                float preA = x0 * W0A[e] + x1 * W1A[e] + x2 * W2A[e] + BBA[e];
                float sigA = frcp(1.f + __expf(-preA));
                float spA  = sigA * (1.f + preA * (1.f - sigA));
                float wsA  = (row == 1) ? W0A[e] : (row == 2) ? W1A[e] : W2A[e];
                float vA   = (row == 0) ? preA * sigA : spA * wsA;
                float preB = x0 * W0B[e] + x1 * W1B[e] + x2 * W2B[e] + BBB[e];
                float sigB = frcp(1.f + __expf(-preB));
                float spB  = sigB * (1.f + preB * (1.f - sigB));
                float wsB  = (row == 1) ? W0B[e] : (row == 2) ? W1B[e] : W2B[e];
                float vB   = (row == 0) ? preB * sigB : spB * wsB;
                hw[e] = packh(vA, vB);
            }
            const int base = (kq << 7) + ((m ^ (kq & 7)) << 2);
            *(uint4*)&lds[base] = *(uint4*)hw;     // plane 0
        }
    }
    __syncthreads();

    // A-frag LDS word bases: slot j = tt&3 (kq = 2*tt+l5 -> kq&7 period 4 in tt).
    int abase[4];
    #pragma unroll
    for (int j = 0; j < 4; ++j) {
        const int kq = 2 * j + l5;
        abase[j] = (kq << 7) + ((ln ^ (kq & 7)) << 2);
    }

    #pragma unroll 1
    for (int l = 0; l < 4; ++l) {
        const int rdoff = (l & 1) ? PP : 0;        // read plane
        const int wroff = (l & 1) ? 0 : PP;        // write plane (epilogue)
        f32x16 acc[2];
        acc[0] = (f32x16)0.0f;
        acc[1] = (f32x16)0.0f;

        #pragma unroll
        for (int tt = 0; tt < 16; ++tt) {          // fully unrolled K-loop
            const int slot = tt & 3;
            // A frag: zero per-step address VALU (base reg + immediate)
            const int aw = rdoff + abase[tt & 3] + (tt >> 2) * 1024;
            FragH a;
            *(uint4*)&a.u[0] = *(const uint4*)&lds[aw];

            // MFMA FIRST, straight from the ring (WAR with refill below;
            // no copies needed -- MFMA reads registers at issue)
            __builtin_amdgcn_s_setprio(1);
            acc[0] = mfma16(a.v, qh[slot][0], acc[0]);
            acc[1] = mfma16(a.v, qh[slot][1], acc[1]);
            __builtin_amdgcn_s_setprio(0);

            // refill this slot with chunk lin+4 (uniform -> scalar pipe)
            int lin = l * 16 + tt + 4;
            if (lin > NCHUNK_TOT - 1) lin = NCHUNK_TOT - 1;
            const uint32_t* Bb = Wp + lin * CHUNK_WORDS + l5 * 1024;
            qh[slot][0] = *(const uint4*)(Bb + n4v);
            qh[slot][1] = *(const uint4*)(Bb + n4v + 128);
        }

        if (l < 3) {
            // bias loads (global, no LDS dependence)
            const float bn0 = b_hid[l * 256 + n1];
            const float bn1 = b_hid[l * 256 + n1 + 32];
            // NO barrier here: epilogue writes the OTHER plane (wroff).
            // C layout per acc: col = n (lane ln), row = st + 8*rg + 4*l5
            // This lane writes pair p = cg*32+ln = cols (n1, n1+32) for 16 rows.
            const int kq    = cg * 8 + (ln >> 2);  // p>>2 ; kq&7 == ln>>2
            const int xr    = ln >> 2;
            const int wbase = wroff + (kq << 7) + (ln & 3);
            #pragma unroll
            for (int rg = 0; rg < 4; ++rg) {
                float v0[4], v1[4];
                {
                    const float pre = acc[0][rg * 4 + 0] + bn0;
                    const float sig = frcp(1.f + __expf(-pre));
                    const float sp  = sig * (1.f + pre * (1.f - sig));
                    v0[0] = pre * sig;
                    v0[1] = sp * acc[0][rg * 4 + 1];
                    v0[2] = sp * acc[0][rg * 4 + 2];
                    v0[3] = sp * acc[0][rg * 4 + 3];
                }
                {
                    const float pre = acc[1][rg * 4 + 0] + bn1;
                    const float sig = frcp(1.f + __expf(-pre));
                    const float sp  = sig * (1.f + pre * (1.f - sig));
                    v1[0] = pre * sig;
                    v1[1] = sp * acc[1][rg * 4 + 1];
                    v1[2] = sp * acc[1][rg * 4 + 2];
                    v1[3] = sp * acc[1][rg * 4 + 3];
                }
                const int mb = 8 * rg + 4 * l5;
                #pragma unroll
                for (int st = 0; st < 4; ++st) {
                    const int a = wbase + (((mb + st) ^ xr) << 2);
                    lds[a] = packh(v0[st], v1[st]);
                }
            }
            __syncthreads();                       // sA(l+1) visible to all
        } else {
            __syncthreads();                       // all waves done READING plane 1
            // dump raw output-GEMM results to E[smp][state][n] fp32 (32 KB,
            // overlays both planes -- sA is dead here)
            float* E = (float*)lds;
            #pragma unroll
            for (int ct = 0; ct < 2; ++ct) {
                const int n = n1 + ct * 32;
                #pragma unroll
                for (int rg = 0; rg < 4; ++rg) {
                    const int smp = 2 * rg + l5;
                    #pragma unroll
                    for (int st = 0; st < 4; ++st)
                        E[(smp * 4 + st) * 256 + n] = acc[ct][rg * 4 + st];
                }
            }
            __syncthreads();
            // final phase: lane = mixture, wave w -> samples 2w..2w+1
            const float4* E4 = (const float4*)lds;
            float4 bo = *(const float4*)&b_out[lane * 4];
            #pragma unroll
            for (int g = 0; g < 2; ++g) {
                const int sl = wave * 2 + g;       // 0..7
                float4 o  = E4[(sl * 4 + 0) * 64 + lane];
                float4 t1 = E4[(sl * 4 + 1) * 64 + lane];
                float4 t2 = E4[(sl * 4 + 2) * 64 + lane];
                float4 t3 = E4[(sl * 4 + 3) * 64 + lane];
                float sm  = o.x + bo.x;
                float oa0 = o.y + bo.y, oa1 = o.z + bo.z, oa2 = o.w + bo.w;
                float ds0 = t1.x, ds1 = t2.x, ds2 = t3.x;
                float mx = wmax(sm);
                float e  = __expf(sm - mx);
                float Z  = wsum(e);
                float rZ = frcp(Z);
                float T0 = wsum(e * ds0) * rZ;
                float T1 = wsum(e * ds1) * rZ;
                float T2 = wsum(e * ds2) * rZ;
                float g0 =  (ds1 - T1) * oa0 + t2.y + (ds2 - T2) * oa1 + t3.z;
                float g1 = -((ds0 - T0) * oa0 + t1.y) + (ds2 - T2) * oa2 + t3.w;
                float g2 = -((ds0 - T0) * oa1 + t1.z) - ((ds1 - T1) * oa2 + t2.w);
                float u0 = wsum(e * g0) * rZ;
                float u1 = wsum(e * g1) * rZ;
                float u2 = wsum(e * g2) * rZ;
                if (lane == 0) {
                    const int sg = s0 + sl;
                    out[sg * 3 + 0] = u0;
                    out[sg * 3 + 1] = u1;
                    out[sg * 3 + 2] = u2;
                }
            }
        }
    }
}

extern "C" void kernel_launch(void* const* d_in, const int* in_sizes, int n_in,
                              void* d_out, int out_size, void* d_ws, size_t ws_size,
                              hipStream_t stream) {
    const float* x     = (const float*)d_in[0];
    const float* w_in  = (const float*)d_in[1];
    const float* b_in  = (const float*)d_in[2];
    const float* w_hid = (const float*)d_in[3];
    const float* b_hid = (const float*)d_in[4];
    const float* w_out = (const float*)d_in[5];
    const float* b_out = (const float*)d_in[6];
    float* out = (float*)d_out;
    uint32_t* Wp = (uint32_t*)d_ws;                 // 1 MB packed-weight image
    const int N = in_sizes[0] / 3;

    pack_w<<<1024, 256, 0, stream>>>(w_hid, w_out, Wp);
    divfree_mfma<<<N / SPB, THREADS, 0, stream>>>(x, Wp, w_in, b_in, b_hid, b_out, out);
}

// Round 8
// 265.831 us; speedup vs baseline: 2.1914x; 1.0446x over previous
//
#include <hip/hip_runtime.h>
#include <stdint.h>

#define THREADS 256
#define SPB 8                  // samples per block -> 32 A-rows
#define CHUNK_WORDS 4096       // one K=16 W chunk: hi plane 2048 + lo plane 2048 words
#define NCHUNK_TOT 64          // 4 layers x 16 chunks, linearized
#define PP 4096                // ping-pong plane stride in words (16 KB)

typedef _Float16 f16x8 __attribute__((ext_vector_type(8)));
typedef float f32x16 __attribute__((ext_vector_type(16)));

union FragH { uint32_t u[4]; f16x8 v; };

__device__ __forceinline__ uint32_t f2h(float f) {     // RNE f32->f16 bits
    _Float16 h = (_Float16)f;                          // v_cvt_f16_f32 (RNE)
    return (uint32_t)__builtin_bit_cast(uint16_t, h);
}
__device__ __forceinline__ float h2f(uint32_t b) {
    return (float)__builtin_bit_cast(_Float16, (uint16_t)(b & 0xffffu));
}
// ONE-OP packed f32x2 -> f16x2 (RTZ). RTZ's extra <=1 ulp operand error is
// proven invisible: absmax was bit-identical (2.441e-4) across 22b/11b A and
// 22b/11b B operand configs (rounds 4-7).
__device__ __forceinline__ uint32_t pkrtz(float a, float b) {
    return __builtin_bit_cast(uint32_t, __builtin_amdgcn_cvt_pkrtz(a, b));
}
__device__ __forceinline__ float frcp(float x) {       // v_rcp_f32 (~1 ulp)
    return __builtin_amdgcn_rcpf(x);
}
__device__ __forceinline__ float wsum(float v) {
    #pragma unroll
    for (int off = 32; off > 0; off >>= 1) v += __shfl_xor(v, off, 64);
    return v;
}
// MFMA with B taken straight from the prefetch ring (no union round-trip;
// avoids forced reg copies across the WAR with the ring refill)
__device__ __forceinline__ f32x16 mfma16(f16x8 a, uint4 b, f32x16 c) {
    return __builtin_amdgcn_mfma_f32_32x32x16_f16(a, __builtin_bit_cast(f16x8, b), c, 0, 0, 0);
}

// ---- pre-kernel: pack W into planar hi/lo f16 k-pair chunk images ----
// word idx = l*65536 + kt*4096 + plane*2048 + s8*1024 + n*4 + w
// PAIR PERMUTATION: pair index kp = kt*8 + s8*4 + w holds logical k's
//   klo(kp) = 2*(kp & ~31) + (kp & 31)   and   khi = klo + 32
// so a lane's two output columns (n, n+32) form one f16 k-pair IN-LANE.
// plane0 = f16 RNE of w; plane1 = residual (UNUSED by the main kernel:
// B hi-only is numerically invisible -- see round 7 evidence).
__global__ __launch_bounds__(256) void pack_w(const float* __restrict__ w_hid,
                                              const float* __restrict__ w_out,
                                              uint32_t* __restrict__ Wp) {
    int idx = blockIdx.x * 256 + threadIdx.x;      // 0..262143
    int l     = idx >> 16;
    int r     = idx & 65535;
    int kt    = r >> 12;
    int r2    = r & 4095;
    int plane = r2 >> 11;
    int r3    = r2 & 2047;
    int s8    = r3 >> 10;
    int n     = (r3 >> 2) & 255;
    int w     = r3 & 3;
    int kp    = kt * 8 + s8 * 4 + w;               // 0..127
    int klo   = 2 * (kp & ~31) + (kp & 31);
    int khi   = klo + 32;
    const float* Wsrc = (l < 3) ? (w_hid + l * 65536) : w_out;
    float a = Wsrc[klo * 256 + n];
    float b = Wsrc[khi * 256 + n];
    uint32_t ha = f2h(a), hb = f2h(b);
    uint32_t word;
    if (plane == 0) {
        word = ha | (hb << 16);
    } else {
        uint32_t la = f2h(a - h2f(ha));
        uint32_t lb = f2h(b - h2f(hb));
        word = la | (lb << 16);
    }
    Wp[idx] = word;
}

// sA layout (single f16 plane, 32 rows): (kq<<7) + ((m ^ (kq&7))<<2) + (kp&3)
// kp = pair index (logical cols klo(kp), klo(kp)+32), kq = kp>>2, m = row 0..31.
// PING-PONG: two 16 KB sA planes at word offsets 0 / PP. Layer l READS plane
// (l&1) and its epilogue WRITES plane ((l+1)&1) -> no pre-epilogue barrier.
// Final phase's fp32 E (8x4x256) overlays the full 32 KB.
//
// Wave tiling: 4 waves, wave w = column group cg (64 cols, two 32-col tiles
// acc[0]/acc[1]); every wave covers ALL 32 rows; col sets DISJOINT across waves.
// Arithmetic: A f16, B f16 hi-only -> 2 mfma/tt (one per col-tile).
// B ring: 4-deep (slot = tt&3, refill lin = l*16+tt+4), 2 loads/tt.
__global__ __launch_bounds__(THREADS, 4) void divfree_mfma(
    const float* __restrict__ x,
    const uint32_t* __restrict__ Wp,
    const float* __restrict__ w_in,
    const float* __restrict__ b_in,
    const float* __restrict__ b_hid,
    const float* __restrict__ b_out,
    float* __restrict__ out)
{
    __shared__ uint32_t lds[8192];                 // 32 KB = 2 ping-pong planes
    const int tid  = threadIdx.x;
    const int wave = tid >> 6, lane = tid & 63;
    const int l5 = lane >> 5, ln = lane & 31;
    const int s0 = blockIdx.x * SPB;
    const int cg = wave;                           // column group (64 cols)
    const int n1 = cg * 64 + ln;                   // lower output column
    const int n4v = n1 * 4;                        // B-frag word offset (ct=1: +128)

    // 4-deep software-pipelined B prefetch (hi plane only), 2 col-tiles/slot
    uint4 qh[4][2];
    #pragma unroll
    for (int c = 0; c < 4; ++c) {
        const uint32_t* Bb = Wp + c * CHUNK_WORDS + l5 * 1024;
        qh[c][0] = *(const uint4*)(Bb + n4v);
        qh[c][1] = *(const uint4*)(Bb + n4v + 128);
    }

    { // ---- input layer: thread owns (kq = tid>>3, sample s = tid&7) ----
      // ONE sigmoid set per 8 cols serves all 4 state rows (r=0: pre*sig;
      // r>=1: sp*W_{r-1}) -> ~3x fewer VALU ops than per-row ownership.
        const int kq = tid >> 3;                   // 0..31
        const int s  = tid & 7;                    // 0..7
        const int kA = ((kq >> 3) << 6) + ((kq & 7) << 2);
        const float x0 = x[(s0 + s) * 3 + 0];
        const float x1 = x[(s0 + s) * 3 + 1];
        const float x2 = x[(s0 + s) * 3 + 2];
        float4 w0A = *(const float4*)&w_in[kA];
        float4 w1A = *(const float4*)&w_in[256 + kA];
        float4 w2A = *(const float4*)&w_in[512 + kA];
        float4 bbA = *(const float4*)&b_in[kA];
        float4 w0B = *(const float4*)&w_in[kA + 32];
        float4 w1B = *(const float4*)&w_in[256 + kA + 32];
        float4 w2B = *(const float4*)&w_in[512 + kA + 32];
        float4 bbB = *(const float4*)&b_in[kA + 32];
        float W0A[4] = {w0A.x, w0A.y, w0A.z, w0A.w};
        float W1A[4] = {w1A.x, w1A.y, w1A.z, w1A.w};
        float W2A[4] = {w2A.x, w2A.y, w2A.z, w2A.w};
        float BBA[4] = {bbA.x, bbA.y, bbA.z, bbA.w};
        float W0B[4] = {w0B.x, w0B.y, w0B.z, w0B.w};
        float W1B[4] = {w1B.x, w1B.y, w1B.z, w1B.w};
        float W2B[4] = {w2B.x, w2B.y, w2B.z, w2B.w};
        float BBB[4] = {bbB.x, bbB.y, bbB.z, bbB.w};
        float preA[4], sigA[4], spA[4], preB[4], sigB[4], spB[4];
        #pragma unroll
        for (int w = 0; w < 4; ++w) {
            preA[w] = x0 * W0A[w] + x1 * W1A[w] + x2 * W2A[w] + BBA[w];
            sigA[w] = frcp(1.f + __expf(-preA[w]));
            spA[w]  = sigA[w] * (1.f + preA[w] * (1.f - sigA[w]));
            preB[w] = x0 * W0B[w] + x1 * W1B[w] + x2 * W2B[w] + BBB[w];
            sigB[w] = frcp(1.f + __expf(-preB[w]));
            spB[w]  = sigB[w] * (1.f + preB[w] * (1.f - sigB[w]));
        }
        const int k3 = kq & 7;
        {   // r = 0 row: h = pre * sig
            uint32_t hw[4];
            #pragma unroll
            for (int w = 0; w < 4; ++w)
                hw[w] = pkrtz(preA[w] * sigA[w], preB[w] * sigB[w]);
            const int m = 4 * s;
            *(uint4*)&lds[(kq << 7) + ((m ^ k3) << 2)] = *(uint4*)hw;
        }
        #pragma unroll
        for (int r = 1; r < 4; ++r) {              // derivative rows: sp * W_{r-1}
            uint32_t hw[4];
            #pragma unroll
            for (int w = 0; w < 4; ++w) {
                float wsA = (r == 1) ? W0A[w] : (r == 2) ? W1A[w] : W2A[w];
                float wsB = (r == 1) ? W0B[w] : (r == 2) ? W1B[w] : W2B[w];
                hw[w] = pkrtz(spA[w] * wsA, spB[w] * wsB);
            }
            const int m = 4 * s + r;
            *(uint4*)&lds[(kq << 7) + ((m ^ k3) << 2)] = *(uint4*)hw;
        }
    }
    __syncthreads();

    // A-frag LDS word bases: slot j = tt&3 (kq = 2*tt+l5 -> kq&7 period 4 in tt).
    int abase[4];
    #pragma unroll
    for (int j = 0; j < 4; ++j) {
        const int kq = 2 * j + l5;
        abase[j] = (kq << 7) + ((ln ^ (kq & 7)) << 2);
    }

    #pragma unroll 1
    for (int l = 0; l < 4; ++l) {
        const int rdoff = (l & 1) ? PP : 0;        // read plane
        const int wroff = (l & 1) ? 0 : PP;        // write plane (epilogue)
        f32x16 acc[2];
        acc[0] = (f32x16)0.0f;
        acc[1] = (f32x16)0.0f;

        #pragma unroll
        for (int tt = 0; tt < 16; ++tt) {          // fully unrolled K-loop
            const int slot = tt & 3;
            // A frag: zero per-step address VALU (base reg + immediate)
            const int aw = rdoff + abase[tt & 3] + (tt >> 2) * 1024;
            FragH a;
            *(uint4*)&a.u[0] = *(const uint4*)&lds[aw];

            // MFMA FIRST, straight from the ring (WAR with refill below;
            // no copies needed -- MFMA reads registers at issue)
            __builtin_amdgcn_s_setprio(1);
            acc[0] = mfma16(a.v, qh[slot][0], acc[0]);
            acc[1] = mfma16(a.v, qh[slot][1], acc[1]);
            __builtin_amdgcn_s_setprio(0);

            // refill this slot with chunk lin+4 (uniform -> scalar pipe)
            int lin = l * 16 + tt + 4;
            if (lin > NCHUNK_TOT - 1) lin = NCHUNK_TOT - 1;
            const uint32_t* Bb = Wp + lin * CHUNK_WORDS + l5 * 1024;
            qh[slot][0] = *(const uint4*)(Bb + n4v);
            qh[slot][1] = *(const uint4*)(Bb + n4v + 128);
        }

        if (l < 3) {
            // bias loads (global, no LDS dependence)
            const float bn0 = b_hid[l * 256 + n1];
            const float bn1 = b_hid[l * 256 + n1 + 32];
            // NO barrier here: epilogue writes the OTHER plane (wroff).
            // C layout per acc: col = n (lane ln), row = st + 8*rg + 4*l5
            // This lane writes pair p = cg*32+ln = cols (n1, n1+32) for 16 rows.
            const int kq    = cg * 8 + (ln >> 2);  // p>>2 ; kq&7 == ln>>2
            const int xr    = ln >> 2;
            const int wbase = wroff + (kq << 7) + (ln & 3);
            #pragma unroll
            for (int rg = 0; rg < 4; ++rg) {
                float v0[4], v1[4];
                {
                    const float pre = acc[0][rg * 4 + 0] + bn0;
                    const float sig = frcp(1.f + __expf(-pre));
                    const float sp  = sig * (1.f + pre * (1.f - sig));
                    v0[0] = pre * sig;
                    v0[1] = sp * acc[0][rg * 4 + 1];
                    v0[2] = sp * acc[0][rg * 4 + 2];
                    v0[3] = sp * acc[0][rg * 4 + 3];
                }
                {
                    const float pre = acc[1][rg * 4 + 0] + bn1;
                    const float sig = frcp(1.f + __expf(-pre));
                    const float sp  = sig * (1.f + pre * (1.f - sig));
                    v1[0] = pre * sig;
                    v1[1] = sp * acc[1][rg * 4 + 1];
                    v1[2] = sp * acc[1][rg * 4 + 2];
                    v1[3] = sp * acc[1][rg * 4 + 3];
                }
                const int mb = 8 * rg + 4 * l5;
                #pragma unroll
                for (int st = 0; st < 4; ++st) {
                    const int a = wbase + (((mb + st) ^ xr) << 2);
                    lds[a] = pkrtz(v0[st], v1[st]);
                }
            }
            __syncthreads();                       // sA(l+1) visible to all
        } else {
            __syncthreads();                       // all waves done READING plane 1
            // dump raw output-GEMM results to E[smp][state][n] fp32 (32 KB,
            // overlays both planes -- sA is dead here)
            float* E = (float*)lds;
            #pragma unroll
            for (int ct = 0; ct < 2; ++ct) {
                const int n = n1 + ct * 32;
                #pragma unroll
                for (int rg = 0; rg < 4; ++rg) {
                    const int smp = 2 * rg + l5;
                    #pragma unroll
                    for (int st = 0; st < 4; ++st)
                        E[(smp * 4 + st) * 256 + n] = acc[ct][rg * 4 + st];
                }
            }
            __syncthreads();
            // final phase: lane = mixture, wave w -> samples 2w..2w+1.
            // No max-subtraction: |logits| << 88, f32 exp cannot overflow.
            const float4* E4 = (const float4*)lds;
            float4 bo = *(const float4*)&b_out[lane * 4];
            #pragma unroll
            for (int g = 0; g < 2; ++g) {
                const int sl = wave * 2 + g;       // 0..7
                float4 o  = E4[(sl * 4 + 0) * 64 + lane];
                float4 t1 = E4[(sl * 4 + 1) * 64 + lane];
                float4 t2 = E4[(sl * 4 + 2) * 64 + lane];
                float4 t3 = E4[(sl * 4 + 3) * 64 + lane];
                float sm  = o.x + bo.x;
                float oa0 = o.y + bo.y, oa1 = o.z + bo.z, oa2 = o.w + bo.w;
                float ds0 = t1.x, ds1 = t2.x, ds2 = t3.x;
                float e  = __expf(sm);
                float Z  = wsum(e);
                float rZ = frcp(Z);
                float T0 = wsum(e * ds0) * rZ;
                float T1 = wsum(e * ds1) * rZ;
                float T2 = wsum(e * ds2) * rZ;
                float g0 =  (ds1 - T1) * oa0 + t2.y + (ds2 - T2) * oa1 + t3.z;
                float g1 = -((ds0 - T0) * oa0 + t1.y) + (ds2 - T2) * oa2 + t3.w;
                float g2 = -((ds0 - T0) * oa1 + t1.z) - ((ds1 - T1) * oa2 + t2.w);
                float u0 = wsum(e * g0) * rZ;
                float u1 = wsum(e * g1) * rZ;
                float u2 = wsum(e * g2) * rZ;
                if (lane == 0) {
                    const int sg = s0 + sl;
                    out[sg * 3 + 0] = u0;
                    out[sg * 3 + 1] = u1;
                    out[sg * 3 + 2] = u2;
                }
            }
        }
    }
}

extern "C" void kernel_launch(void* const* d_in, const int* in_sizes, int n_in,
                              void* d_out, int out_size, void* d_ws, size_t ws_size,
                              hipStream_t stream) {
    const float* x     = (const float*)d_in[0];
    const float* w_in  = (const float*)d_in[1];
    const float* b_in  = (const float*)d_in[2];
    const float* w_hid = (const float*)d_in[3];
    const float* b_hid = (const float*)d_in[4];
    const float* w_out = (const float*)d_in[5];
    const float* b_out = (const float*)d_in[6];
    float* out = (float*)d_out;
    uint32_t* Wp = (uint32_t*)d_ws;                 // 1 MB packed-weight image
    const int N = in_sizes[0] / 3;

    pack_w<<<1024, 256, 0, stream>>>(w_hid, w_out, Wp);
    divfree_mfma<<<N / SPB, THREADS, 0, stream>>>(x, Wp, w_in, b_in, b_hid, b_out, out);
}

// Round 9
// 262.647 us; speedup vs baseline: 2.2179x; 1.0121x over previous
//
#include <hip/hip_runtime.h>
#include <stdint.h>

#define THREADS 256
#define SPB 8                  // samples per block -> 32 A-rows
#define CHUNK_WORDS 2048       // one K=16 W chunk: dense f16-hi image (8 KB)
#define NCHUNK_TOT 64          // 4 layers x 16 chunks, linearized
#define PP 4096                // ping-pong plane stride in words (16 KB)

typedef _Float16 f16x8 __attribute__((ext_vector_type(8)));
typedef float f32x16 __attribute__((ext_vector_type(16)));

union FragH { uint32_t u[4]; f16x8 v; };

// ONE-OP packed f32x2 -> f16x2 (RTZ). RTZ's extra <=1 ulp operand error is
// proven invisible: absmax was bit-identical (2.441e-4) across 22b/11b A,
// 22b/11b B, and RTZ-activation configs (rounds 4-8).
__device__ __forceinline__ uint32_t pkrtz(float a, float b) {
    return __builtin_bit_cast(uint32_t, __builtin_amdgcn_cvt_pkrtz(a, b));
}
__device__ __forceinline__ float frcp(float x) {       // v_rcp_f32 (~1 ulp)
    return __builtin_amdgcn_rcpf(x);
}
__device__ __forceinline__ float wsum(float v) {
    #pragma unroll
    for (int off = 32; off > 0; off >>= 1) v += __shfl_xor(v, off, 64);
    return v;
}
// MFMA with B taken straight from the prefetch ring (no union round-trip;
// avoids forced reg copies across the WAR with the ring refill)
__device__ __forceinline__ f32x16 mfma16(f16x8 a, uint4 b, f32x16 c) {
    return __builtin_amdgcn_mfma_f32_32x32x16_f16(a, __builtin_bit_cast(f16x8, b), c, 0, 0, 0);
}

// ---- pre-kernel: pack W into a DENSE f16-hi k-pair chunk image (512 KB) ----
// word idx = l*32768 + kt*2048 + s8*1024 + n*4 + w
// PAIR PERMUTATION: pair index kp = kt*8 + s8*4 + w holds logical k's
//   klo(kp) = 2*(kp & ~31) + (kp & 31)   and   khi = klo + 32
// so a lane's two output columns (n, n+32) form one f16 k-pair IN-LANE.
// Thread owns (l,kt,s8,n) and emits one uint4 (w=0..3): every load and the
// store are lane-consecutive -> fully coalesced (old layout strided loads by
// 256 floats and wrote a lo plane that has been unused since round 7).
__global__ __launch_bounds__(256) void pack_w(const float* __restrict__ w_hid,
                                              const float* __restrict__ w_out,
                                              uint32_t* __restrict__ Wp) {
    int t  = blockIdx.x * 256 + threadIdx.x;       // 0..32767
    int l  = t >> 13;
    int r  = t & 8191;
    int kt = r >> 9;
    int r2 = r & 511;
    int s8 = r2 >> 8;
    int n  = r2 & 255;
    const float* Wsrc = (l < 3) ? (w_hid + l * 65536) : w_out;
    uint32_t wd[4];
    #pragma unroll
    for (int w = 0; w < 4; ++w) {
        int kp  = kt * 8 + s8 * 4 + w;             // 0..127
        int klo = 2 * (kp & ~31) + (kp & 31);
        wd[w] = pkrtz(Wsrc[klo * 256 + n], Wsrc[(klo + 32) * 256 + n]);
    }
    *(uint4*)&Wp[l * 32768 + kt * 2048 + s8 * 1024 + n * 4] = *(uint4*)wd;
}

// sA layout (single f16 plane, 32 rows): (kq<<7) + ((m ^ (kq&7))<<2) + (kp&3)
// kp = pair index (logical cols klo(kp), klo(kp)+32), kq = kp>>2, m = row 0..31.
// PING-PONG: two 16 KB sA planes at word offsets 0 / PP. Layer l READS plane
// (l&1) and its epilogue WRITES plane ((l+1)&1) -> no pre-epilogue barrier.
// Final phase's fp32 E (8x4x256) overlays the full 32 KB.
//
// Wave tiling: 4 waves, wave w = column group cg (64 cols, two 32-col tiles
// acc[0]/acc[1]); every wave covers ALL 32 rows; col sets DISJOINT across waves.
// Arithmetic: A f16, B f16 hi-only -> 2 mfma/tt (one per col-tile).
// B ring: 4-deep (slot = tt&3, refill lin = l*16+tt+4), 2 loads/tt.
__global__ __launch_bounds__(THREADS, 4) void divfree_mfma(
    const float* __restrict__ x,
    const uint32_t* __restrict__ Wp,
    const float* __restrict__ w_in,
    const float* __restrict__ b_in,
    const float* __restrict__ b_hid,
    const float* __restrict__ b_out,
    float* __restrict__ out)
{
    __shared__ uint32_t lds[8192];                 // 32 KB = 2 ping-pong planes
    const int tid  = threadIdx.x;
    const int wave = tid >> 6, lane = tid & 63;
    const int l5 = lane >> 5, ln = lane & 31;
    const int s0 = blockIdx.x * SPB;
    const int cg = wave;                           // column group (64 cols)
    const int n1 = cg * 64 + ln;                   // lower output column
    const int n4v = n1 * 4;                        // B-frag word offset (ct=1: +128)

    // 4-deep software-pipelined B prefetch (hi image), 2 col-tiles/slot
    uint4 qh[4][2];
    #pragma unroll
    for (int c = 0; c < 4; ++c) {
        const uint32_t* Bb = Wp + c * CHUNK_WORDS + l5 * 1024;
        qh[c][0] = *(const uint4*)(Bb + n4v);
        qh[c][1] = *(const uint4*)(Bb + n4v + 128);
    }

    { // ---- input layer: thread owns (kq = tid&31, sample s = tid>>5) ----
      // ONE sigmoid set per 8 cols serves all 4 state rows (r=0: pre*sig;
      // r>=1: sp*W_{r-1}). kq in the LOW tid bits -> within any 16-lane
      // group kq&7 spans all 8 bank-quads -> conflict-free LDS writes
      // (round 8's kq=tid>>3 mapping was a 4-way conflict: 4.19M/dispatch).
        const int kq = tid & 31;                   // 0..31
        const int s  = tid >> 5;                   // 0..7
        const int kA = ((kq >> 3) << 6) + ((kq & 7) << 2);
        const float x0 = x[(s0 + s) * 3 + 0];
        const float x1 = x[(s0 + s) * 3 + 1];
        const float x2 = x[(s0 + s) * 3 + 2];
        float4 w0A = *(const float4*)&w_in[kA];
        float4 w1A = *(const float4*)&w_in[256 + kA];
        float4 w2A = *(const float4*)&w_in[512 + kA];
        float4 bbA = *(const float4*)&b_in[kA];
        float4 w0B = *(const float4*)&w_in[kA + 32];
        float4 w1B = *(const float4*)&w_in[256 + kA + 32];
        float4 w2B = *(const float4*)&w_in[512 + kA + 32];
        float4 bbB = *(const float4*)&b_in[kA + 32];
        float W0A[4] = {w0A.x, w0A.y, w0A.z, w0A.w};
        float W1A[4] = {w1A.x, w1A.y, w1A.z, w1A.w};
        float W2A[4] = {w2A.x, w2A.y, w2A.z, w2A.w};
        float BBA[4] = {bbA.x, bbA.y, bbA.z, bbA.w};
        float W0B[4] = {w0B.x, w0B.y, w0B.z, w0B.w};
        float W1B[4] = {w1B.x, w1B.y, w1B.z, w1B.w};
        float W2B[4] = {w2B.x, w2B.y, w2B.z, w2B.w};
        float BBB[4] = {bbB.x, bbB.y, bbB.z, bbB.w};
        float preA[4], sigA[4], spA[4], preB[4], sigB[4], spB[4];
        #pragma unroll
        for (int w = 0; w < 4; ++w) {
            preA[w] = x0 * W0A[w] + x1 * W1A[w] + x2 * W2A[w] + BBA[w];
            sigA[w] = frcp(1.f + __expf(-preA[w]));
            spA[w]  = sigA[w] * (1.f + preA[w] * (1.f - sigA[w]));
            preB[w] = x0 * W0B[w] + x1 * W1B[w] + x2 * W2B[w] + BBB[w];
            sigB[w] = frcp(1.f + __expf(-preB[w]));
            spB[w]  = sigB[w] * (1.f + preB[w] * (1.f - sigB[w]));
        }
        const int k3 = kq & 7;
        {   // r = 0 row: h = pre * sig
            uint32_t hw[4];
            #pragma unroll
            for (int w = 0; w < 4; ++w)
                hw[w] = pkrtz(preA[w] * sigA[w], preB[w] * sigB[w]);
            const int m = 4 * s;
            *(uint4*)&lds[(kq << 7) + ((m ^ k3) << 2)] = *(uint4*)hw;
        }
        #pragma unroll
        for (int r = 1; r < 4; ++r) {              // derivative rows: sp * W_{r-1}
            uint32_t hw[4];
            #pragma unroll
            for (int w = 0; w < 4; ++w) {
                float wsA = (r == 1) ? W0A[w] : (r == 2) ? W1A[w] : W2A[w];
                float wsB = (r == 1) ? W0B[w] : (r == 2) ? W1B[w] : W2B[w];
                hw[w] = pkrtz(spA[w] * wsA, spB[w] * wsB);
            }
            const int m = 4 * s + r;
            *(uint4*)&lds[(kq << 7) + ((m ^ k3) << 2)] = *(uint4*)hw;
        }
    }
    __syncthreads();

    // A-frag LDS word bases: slot j = tt&3 (kq = 2*tt+l5 -> kq&7 period 4 in tt).
    int abase[4];
    #pragma unroll
    for (int j = 0; j < 4; ++j) {
        const int kq = 2 * j + l5;
        abase[j] = (kq << 7) + ((ln ^ (kq & 7)) << 2);
    }

    #pragma unroll 1
    for (int l = 0; l < 4; ++l) {
        const int rdoff = (l & 1) ? PP : 0;        // read plane
        const int wroff = (l & 1) ? 0 : PP;        // write plane (epilogue)
        f32x16 acc[2];
        acc[0] = (f32x16)0.0f;
        acc[1] = (f32x16)0.0f;

        #pragma unroll
        for (int tt = 0; tt < 16; ++tt) {          // fully unrolled K-loop
            const int slot = tt & 3;
            // A frag: zero per-step address VALU (base reg + immediate)
            const int aw = rdoff + abase[tt & 3] + (tt >> 2) * 1024;
            FragH a;
            *(uint4*)&a.u[0] = *(const uint4*)&lds[aw];

            // MFMA FIRST, straight from the ring (WAR with refill below;
            // no copies needed -- MFMA reads registers at issue)
            __builtin_amdgcn_s_setprio(1);
            acc[0] = mfma16(a.v, qh[slot][0], acc[0]);
            acc[1] = mfma16(a.v, qh[slot][1], acc[1]);
            __builtin_amdgcn_s_setprio(0);

            // refill this slot with chunk lin+4 (uniform -> scalar pipe)
            int lin = l * 16 + tt + 4;
            if (lin > NCHUNK_TOT - 1) lin = NCHUNK_TOT - 1;
            const uint32_t* Bb = Wp + lin * CHUNK_WORDS + l5 * 1024;
            qh[slot][0] = *(const uint4*)(Bb + n4v);
            qh[slot][1] = *(const uint4*)(Bb + n4v + 128);
        }

        if (l < 3) {
            // bias loads (global, no LDS dependence)
            const float bn0 = b_hid[l * 256 + n1];
            const float bn1 = b_hid[l * 256 + n1 + 32];
            // NO barrier here: epilogue writes the OTHER plane (wroff).
            // C layout per acc: col = n (lane ln), row = st + 8*rg + 4*l5
            // This lane writes pair p = cg*32+ln = cols (n1, n1+32) for 16 rows.
            const int kq    = cg * 8 + (ln >> 2);  // p>>2 ; kq&7 == ln>>2
            const int xr    = ln >> 2;
            const int wbase = wroff + (kq << 7) + (ln & 3);
            #pragma unroll
            for (int rg = 0; rg < 4; ++rg) {
                float v0[4], v1[4];
                {
                    const float pre = acc[0][rg * 4 + 0] + bn0;
                    const float sig = frcp(1.f + __expf(-pre));
                    const float sp  = sig * (1.f + pre * (1.f - sig));
                    v0[0] = pre * sig;
                    v0[1] = sp * acc[0][rg * 4 + 1];
                    v0[2] = sp * acc[0][rg * 4 + 2];
                    v0[3] = sp * acc[0][rg * 4 + 3];
                }
                {
                    const float pre = acc[1][rg * 4 + 0] + bn1;
                    const float sig = frcp(1.f + __expf(-pre));
                    const float sp  = sig * (1.f + pre * (1.f - sig));
                    v1[0] = pre * sig;
                    v1[1] = sp * acc[1][rg * 4 + 1];
                    v1[2] = sp * acc[1][rg * 4 + 2];
                    v1[3] = sp * acc[1][rg * 4 + 3];
                }
                const int mb = 8 * rg + 4 * l5;
                #pragma unroll
                for (int st = 0; st < 4; ++st) {
                    const int a = wbase + (((mb + st) ^ xr) << 2);
                    lds[a] = pkrtz(v0[st], v1[st]);
                }
            }
            __syncthreads();                       // sA(l+1) visible to all
        } else {
            __syncthreads();                       // all waves done READING plane 1
            // dump raw output-GEMM results to E[smp][state][n] fp32 (32 KB,
            // overlays both planes -- sA is dead here)
            float* E = (float*)lds;
            #pragma unroll
            for (int ct = 0; ct < 2; ++ct) {
                const int n = n1 + ct * 32;
                #pragma unroll
                for (int rg = 0; rg < 4; ++rg) {
                    const int smp = 2 * rg + l5;
                    #pragma unroll
                    for (int st = 0; st < 4; ++st)
                        E[(smp * 4 + st) * 256 + n] = acc[ct][rg * 4 + st];
                }
            }
            __syncthreads();
            // final phase: lane = mixture, wave w -> samples 2w..2w+1.
            // No max-subtraction: |logits| << 88, f32 exp cannot overflow.
            const float4* E4 = (const float4*)lds;
            float4 bo = *(const float4*)&b_out[lane * 4];
            #pragma unroll
            for (int g = 0; g < 2; ++g) {
                const int sl = wave * 2 + g;       // 0..7
                float4 o  = E4[(sl * 4 + 0) * 64 + lane];
                float4 t1 = E4[(sl * 4 + 1) * 64 + lane];
                float4 t2 = E4[(sl * 4 + 2) * 64 + lane];
                float4 t3 = E4[(sl * 4 + 3) * 64 + lane];
                float sm  = o.x + bo.x;
                float oa0 = o.y + bo.y, oa1 = o.z + bo.z, oa2 = o.w + bo.w;
                float ds0 = t1.x, ds1 = t2.x, ds2 = t3.x;
                float e  = __expf(sm);
                float Z  = wsum(e);
                float rZ = frcp(Z);
                float T0 = wsum(e * ds0) * rZ;
                float T1 = wsum(e * ds1) * rZ;
                float T2 = wsum(e * ds2) * rZ;
                float g0 =  (ds1 - T1) * oa0 + t2.y + (ds2 - T2) * oa1 + t3.z;
                float g1 = -((ds0 - T0) * oa0 + t1.y) + (ds2 - T2) * oa2 + t3.w;
                float g2 = -((ds0 - T0) * oa1 + t1.z) - ((ds1 - T1) * oa2 + t2.w);
                float u0 = wsum(e * g0) * rZ;
                float u1 = wsum(e * g1) * rZ;
                float u2 = wsum(e * g2) * rZ;
                if (lane == 0) {
                    const int sg = s0 + sl;
                    out[sg * 3 + 0] = u0;
                    out[sg * 3 + 1] = u1;
                    out[sg * 3 + 2] = u2;
                }
            }
        }
    }
}

extern "C" void kernel_launch(void* const* d_in, const int* in_sizes, int n_in,
                              void* d_out, int out_size, void* d_ws, size_t ws_size,
                              hipStream_t stream) {
    const float* x     = (const float*)d_in[0];
    const float* w_in  = (const float*)d_in[1];
    const float* b_in  = (const float*)d_in[2];
    const float* w_hid = (const float*)d_in[3];
    const float* b_hid = (const float*)d_in[4];
    const float* w_out = (const float*)d_in[5];
    const float* b_out = (const float*)d_in[6];
    float* out = (float*)d_out;
    uint32_t* Wp = (uint32_t*)d_ws;                 // 512 KB packed-weight image
    const int N = in_sizes[0] / 3;

    pack_w<<<128, 256, 0, stream>>>(w_hid, w_out, Wp);
    divfree_mfma<<<N / SPB, THREADS, 0, stream>>>(x, Wp, w_in, b_in, b_hid, b_out, out);
}